// Round 9
// baseline (759.224 us; speedup 1.0000x reference)
//
#include <hip/hip_runtime.h>
#include <hip/hip_bf16.h>

// Sizes
#define B_ 8
#define S_ 128
#define D_ 512
#define N_ 64
#define H_ 128

// ws offsets (in floats)
#define OFF_WX      0
#define OFF_PX      65536
#define OFF_X       131072     // X (k_attn -> k_gx), later reused as GX2
#define OFF_GX2     131072     // GX2 (k_gx2 -> k_lstm2); X is dead by then
#define OFF_GXF     655360
#define OFF_GXR     1179648
#define OFF_HF      1703936
#define OFF_HR      1835008
#define OFF_BPKF    1966080    // ushort[196608] packed bf16 Whh_f (hi/lo, K=384)
#define OFF_BPKR    2064384    // ushort[196608]
#define OFF_BPK2    2162688    // ushort[196608]
#define OFF_WIHTQ_F 2490368
#define OFF_WIHTQ_R 2752512
#define OFF_WIHT2Q  3014656
#define OFF_BIASF   3342336
#define OFF_BIASR   3342848
#define OFF_BIAS2   3343360

typedef short bf16x8 __attribute__((ext_vector_type(8)));
typedef float f32x4 __attribute__((ext_vector_type(4)));

__device__ __forceinline__ float sigf(float x) { return 1.0f / (1.0f + expf(-x)); }
__device__ __forceinline__ unsigned short f2bf(float x) {
    unsigned u = __float_as_uint(x);
    return (unsigned short)((u + 0x7FFFu + ((u >> 16) & 1u)) >> 16);   // RNE
}
__device__ __forceinline__ float bf2f(unsigned short h) {
    return __uint_as_float(((unsigned)h) << 16);
}

// ---------------- K0: weight transposes + bf16 hi/lo Whh packing + bias sums ----------------
// Bpk layout: o = ((kf*512 + n)*4 + hi)*8 + e ; kcat = kf*32 + hi*8 + e in [0,384)
//   kcat <128: w_hi[kcat]   (pairs h_hi)
//   128-255 : w_lo[kcat-128](pairs h_hi)
//   >=256   : w_hi[kcat-256](pairs h_lo)
__global__ __launch_bounds__(256) void k_prep(
    const float* __restrict__ Wih_f, const float* __restrict__ Wih_r,
    const float* __restrict__ Wih2,
    const float* __restrict__ Whh_f, const float* __restrict__ Whh_r,
    const float* __restrict__ Whh2,
    const float* __restrict__ bih_f, const float* __restrict__ bhh_f,
    const float* __restrict__ bih_r, const float* __restrict__ bhh_r,
    const float* __restrict__ bih2, const float* __restrict__ bhh2,
    float* __restrict__ wihTq_f, float* __restrict__ wihTq_r,
    float* __restrict__ wihT2q,
    unsigned short* __restrict__ BpkF, unsigned short* __restrict__ BpkR,
    unsigned short* __restrict__ Bpk2,
    float* __restrict__ biasf, float* __restrict__ biasr, float* __restrict__ bias2)
{
    int idx = blockIdx.x * blockDim.x + threadIdx.x;
    int stride = gridDim.x * blockDim.x;
    for (int o = idx; o < 262144; o += stride) {
        int q = o >> 11, rem = o & 2047, j = rem >> 2, e = rem & 3;
        int k = 4 * q + e;
        wihTq_f[o] = Wih_f[j * 512 + k];
        wihTq_r[o] = Wih_r[j * 512 + k];
    }
    for (int o = idx; o < 131072; o += stride) {
        int q = o >> 11, rem = o & 2047, j = rem >> 2, e = rem & 3;
        int k = 4 * q + e;
        wihT2q[o] = Wih2[j * 256 + k];
    }
    for (int o = idx; o < 196608; o += stride) {
        int e = o & 7, hi = (o >> 3) & 3, n = (o >> 5) & 511, kf = o >> 14;
        int kcat = kf * 32 + hi * 8 + e;
        int k = kcat & 127;
        bool mid = (kcat >= 128) && (kcat < 256);
        float wf = Whh_f[n * 128 + k];
        unsigned short h1 = f2bf(wf);
        BpkF[o] = mid ? f2bf(wf - bf2f(h1)) : h1;
        float wr = Whh_r[n * 128 + k];
        unsigned short h2 = f2bf(wr);
        BpkR[o] = mid ? f2bf(wr - bf2f(h2)) : h2;
        float w2 = Whh2[n * 128 + k];
        unsigned short h3 = f2bf(w2);
        Bpk2[o] = mid ? f2bf(w2 - bf2f(h3)) : h3;
    }
    if (idx < 512) {
        biasf[idx] = bih_f[idx] + bhh_f[idx];
        biasr[idx] = bih_r[idx] + bhh_r[idx];
        bias2[idx] = bih2[idx] + bhh2[idx];
    }
}

// ---------------- K1: Wx = A@Wx_W^T + b ; Px = A@Wxh_W^T + b ----------------
__global__ __launch_bounds__(64) void k_qk(
    const float* __restrict__ A,
    const float* __restrict__ WxW, const float* __restrict__ Wxb,
    const float* __restrict__ WxhW, const float* __restrict__ Wxhb,
    float* __restrict__ WX, float* __restrict__ PX)
{
    int bs = blockIdx.x;
    int n = threadIdx.x;
    const float* arow = A + bs * 512;
    const float* wr = WxW + n * 512;
    const float* pr = WxhW + n * 512;
    float aw = 0.f, ap = 0.f;
    #pragma unroll 8
    for (int k = 0; k < 512; k += 4) {
        float4 a = *(const float4*)(arow + k);
        float4 w = *(const float4*)(wr + k);
        float4 p = *(const float4*)(pr + k);
        aw += a.x * w.x + a.y * w.y + a.z * w.z + a.w * w.w;
        ap += a.x * p.x + a.y * p.y + a.z * p.z + a.w * p.w;
    }
    WX[bs * 64 + n] = aw + Wxb[n];
    PX[bs * 64 + n] = ap + Wxhb[n];
}

// ---------------- K2: attention scores + X = scores@A ----------------
__global__ __launch_bounds__(256) void k_attn(
    const float* __restrict__ A,
    const float* __restrict__ WX, const float* __restrict__ PX,
    const float* __restrict__ AttW, const float* __restrict__ Attb,
    float* __restrict__ X)
{
    int b = blockIdx.x >> 5;
    int i0 = (blockIdx.x & 31) * 4;
    int tid = threadIdx.x;
    __shared__ float px[128][65];
    __shared__ float wx[4][64];
    __shared__ float aw[64];
    __shared__ float sc[128][4];

    const float* pxg = PX + b * 8192;
    for (int q = tid; q < 2048; q += 256) {
        int j = q >> 4, nq = (q & 15) * 4;
        float4 v = *(const float4*)(pxg + j * 64 + nq);
        px[j][nq] = v.x; px[j][nq + 1] = v.y; px[j][nq + 2] = v.z; px[j][nq + 3] = v.w;
    }
    if (tid < 64) {
        aw[tid] = AttW[tid];
        #pragma unroll
        for (int ii = 0; ii < 4; ii++)
            wx[ii][tid] = WX[b * 8192 + (i0 + ii) * 64 + tid];
    }
    __syncthreads();
    float attb = Attb[0];
    for (int p = tid; p < 512; p += 256) {
        int ii = p >> 7, j = p & 127;
        float acc = 0.f;
        #pragma unroll 4
        for (int n = 0; n < 64; n++) {
            acc += tanhf(px[j][n] + wx[ii][n]) * aw[n];
        }
        sc[j][ii] = sigf(acc + attb);
    }
    __syncthreads();
    int half = tid >> 7;
    int dq = (tid & 127) * 4;
    int ii0 = half * 2;
    float4 acc0 = {0, 0, 0, 0}, acc1 = {0, 0, 0, 0};
    const float* Ab = A + b * 65536;
    for (int j = 0; j < 128; j++) {
        float4 av = *(const float4*)(Ab + j * 512 + dq);
        float s0 = sc[j][ii0], s1 = sc[j][ii0 + 1];
        acc0.x += av.x * s0; acc0.y += av.y * s0; acc0.z += av.z * s0; acc0.w += av.w * s0;
        acc1.x += av.x * s1; acc1.y += av.y * s1; acc1.z += av.z * s1; acc1.w += av.w * s1;
    }
    float* Xp = X + b * 65536;
    *(float4*)(Xp + (i0 + ii0) * 512 + dq) = acc0;
    *(float4*)(Xp + (i0 + ii0 + 1) * 512 + dq) = acc1;
}

// ---------------- K3: gxf = X@Wih_f^T + bias ; gxr (time-reversed rows) ----------------
__global__ __launch_bounds__(512) void k_gx(
    const float* __restrict__ X,
    const float* __restrict__ wihTq_f, const float* __restrict__ wihTq_r,
    const float* __restrict__ biasf, const float* __restrict__ biasr,
    float* __restrict__ GXF, float* __restrict__ GXR)
{
    int r0 = blockIdx.x * 8;
    int j = threadIdx.x;
    float bf = biasf[j], br = biasr[j];
    float af[8], ar[8];
    #pragma unroll
    for (int s = 0; s < 8; s++) { af[s] = bf; ar[s] = br; }
    for (int q = 0; q < 128; q++) {
        float4 wf = *(const float4*)(wihTq_f + q * 2048 + j * 4);
        float4 wr = *(const float4*)(wihTq_r + q * 2048 + j * 4);
        #pragma unroll
        for (int s = 0; s < 8; s++) {
            float4 xv = *(const float4*)(X + (r0 + s) * 512 + 4 * q);
            af[s] += xv.x * wf.x + xv.y * wf.y + xv.z * wf.z + xv.w * wf.w;
            ar[s] += xv.x * wr.x + xv.y * wr.y + xv.z * wr.z + xv.w * wr.w;
        }
    }
    #pragma unroll
    for (int s = 0; s < 8; s++) {
        int r = r0 + s, b = r >> 7, ss = r & 127;
        GXF[r * 512 + j] = af[s];
        GXR[(b * 128 + (127 - ss)) * 512 + j] = ar[s];
    }
}

// ================= MFMA LSTM recurrence core =================
// One block = one direction; M = 8 batches. gates[8x512] = H[8x128] @ WhhT via
// 16x16x32 bf16 MFMA with K=384 hi/lo concatenation (3-term split product).
// 8 waves x (4 n-tiles of 16) ; B frags pinned in AGPRs (192 regs, MFMA-legal).
#define PINB(kf) asm volatile("" : "+a"(bfr[kf][0]), "+a"(bfr[kf][1]), "+a"(bfr[kf][2]), "+a"(bfr[kf][3]));

template<int DO_HOUT, int DO_FIN>
__device__ __forceinline__ void lstm_core(
    const float* __restrict__ gx,          // [(b*128 + t)*512 + n]
    const unsigned short* __restrict__ Bpk,
    float* __restrict__ hout,              // [(b*128 + tout)*128 + hh]
    int rev,
    float (*gatebuf)[128][8],
    unsigned short (*ahi)[136], unsigned short (*alo)[136],
    float (*hfin)[128])
{
    int tid = threadIdx.x;
    int w = tid >> 6;
    int l = tid & 63;
    int lo4 = l & 15, hi4 = l >> 4;

    // load B fragments (one-time): 12 k-frags x 4 n-tiles
    bf16x8 bfr[12][4];
    #pragma unroll
    for (int kf = 0; kf < 12; kf++)
        #pragma unroll
        for (int nt = 0; nt < 4; nt++) {
            int n = w * 64 + nt * 16 + lo4;
            bfr[kf][nt] = *(const bf16x8*)(Bpk + (((kf * 512 + n) * 4 + hi4) << 3));
        }
    PINB(0) PINB(1) PINB(2) PINB(3) PINB(4) PINB(5)
    PINB(6) PINB(7) PINB(8) PINB(9) PINB(10) PINB(11)

    // zero h staging (h0 = 0)
    for (int i = tid; i < 8 * 136; i += 512) {
        ((unsigned short*)ahi)[i] = 0;
        ((unsigned short*)alo)[i] = 0;
    }
    int hh0 = tid >> 3, bb = tid & 7;     // this thread's two (hh, b) state pairs
    float c0 = 0.f, c1 = 0.f;
    __syncthreads();

    for (int t = 0; t < 128; t++) {
        // issue this step's gx gate loads early (consumed after MFMA phase)
        float gxp[8];
        const float* gxt = gx + (bb * 128 + t) * 512;
        #pragma unroll
        for (int gti = 0; gti < 4; gti++) {
            gxp[gti]     = gxt[gti * 128 + hh0];
            gxp[4 + gti] = gxt[gti * 128 + hh0 + 64];
        }

        // MFMA phase: acc[nt] = sum over K=384 of A x B
        f32x4 acc[4];
        #pragma unroll
        for (int nt = 0; nt < 4; nt++) acc[nt] = (f32x4){0.f, 0.f, 0.f, 0.f};
        #pragma unroll
        for (int g = 0; g < 3; g++) {
            bf16x8 af[4];
            #pragma unroll
            for (int kk = 0; kk < 4; kk++) {
                const unsigned short* src = (g < 2) ? &ahi[l & 7][kk * 32 + hi4 * 8]
                                                    : &alo[l & 7][kk * 32 + hi4 * 8];
                af[kk] = *(const bf16x8*)src;
            }
            #pragma unroll
            for (int kk = 0; kk < 4; kk++)
                #pragma unroll
                for (int nt = 0; nt < 4; nt++)
                    acc[nt] = __builtin_amdgcn_mfma_f32_16x16x32_bf16(
                        af[kk], bfr[g * 4 + kk][nt], acc[nt], 0, 0, 0);
        }

        // raw gate sums -> LDS (C rows 0..7 = lanes 0..31)
        if (hi4 < 2) {
            int gtype = w >> 1;
            int hb = (w & 1) * 64;
            #pragma unroll
            for (int nt = 0; nt < 4; nt++)
                *(f32x4*)&gatebuf[gtype][hb + nt * 16 + lo4][hi4 * 4] = acc[nt];
        }
        __syncthreads();

        // c/h update: 2 pairs per thread; activations here (split across all 512 thr)
        {
            float iv = gatebuf[0][hh0][bb] + gxp[0];
            float fv = gatebuf[1][hh0][bb] + gxp[1];
            float gv = gatebuf[2][hh0][bb] + gxp[2];
            float ov = gatebuf[3][hh0][bb] + gxp[3];
            c0 = sigf(fv) * c0 + sigf(iv) * tanhf(gv);
            float hn = sigf(ov) * tanhf(c0);
            unsigned short hhi = f2bf(hn);
            unsigned short hlo = f2bf(hn - bf2f(hhi));
            ahi[bb][hh0] = hhi;
            alo[bb][hh0] = hlo;
            if (DO_HOUT) hout[(bb * 128 + (rev ? 127 - t : t)) * 128 + hh0] = hn;
            if (DO_FIN) hfin[bb][hh0] = hn;
        }
        {
            int hh = hh0 + 64;
            float iv = gatebuf[0][hh][bb] + gxp[4];
            float fv = gatebuf[1][hh][bb] + gxp[5];
            float gv = gatebuf[2][hh][bb] + gxp[6];
            float ov = gatebuf[3][hh][bb] + gxp[7];
            c1 = sigf(fv) * c1 + sigf(iv) * tanhf(gv);
            float hn = sigf(ov) * tanhf(c1);
            unsigned short hhi = f2bf(hn);
            unsigned short hlo = f2bf(hn - bf2f(hhi));
            ahi[bb][hh] = hhi;
            alo[bb][hh] = hlo;
            if (DO_HOUT) hout[(bb * 128 + (rev ? 127 - t : t)) * 128 + hh] = hn;
            if (DO_FIN) hfin[bb][hh] = hn;
        }
        __syncthreads();
    }
}

// ---------------- K4: BiLSTM recurrence (grid=2: dir) ----------------
__global__ __attribute__((amdgpu_waves_per_eu(2, 2))) __launch_bounds__(512)
void k_lstm_bi(const float* __restrict__ GXF, const float* __restrict__ GXR,
               const unsigned short* __restrict__ BpkF,
               const unsigned short* __restrict__ BpkR,
               float* __restrict__ HF, float* __restrict__ HR)
{
    __shared__ __align__(16) float gatebuf[4][128][8];
    __shared__ __align__(16) unsigned short ahi[8][136];
    __shared__ __align__(16) unsigned short alo[8][136];
    int dir = blockIdx.x;
    lstm_core<1, 0>(dir ? GXR : GXF, dir ? BpkR : BpkF, dir ? HR : HF, dir,
                    gatebuf, ahi, alo, nullptr);
}

// ---------------- K5: gx2 = [hf|hr]@Wih2^T + bias2 ----------------
__global__ __launch_bounds__(512) void k_gx2(
    const float* __restrict__ HF, const float* __restrict__ HR,
    const float* __restrict__ wihT2q, const float* __restrict__ bias2,
    float* __restrict__ GX2)
{
    int r0 = blockIdx.x * 8;
    int j = threadIdx.x;
    float bb = bias2[j];
    float a[8];
    #pragma unroll
    for (int s = 0; s < 8; s++) a[s] = bb;
    for (int q = 0; q < 32; q++) {
        float4 w = *(const float4*)(wihT2q + q * 2048 + j * 4);
        #pragma unroll
        for (int s = 0; s < 8; s++) {
            int r = r0 + s;
            float4 xv = *(const float4*)(HF + r * 128 + 4 * q);
            a[s] += xv.x * w.x + xv.y * w.y + xv.z * w.z + xv.w * w.w;
        }
    }
    for (int q = 32; q < 64; q++) {
        float4 w = *(const float4*)(wihT2q + q * 2048 + j * 4);
        #pragma unroll
        for (int s = 0; s < 8; s++) {
            int r = r0 + s;
            float4 xv = *(const float4*)(HR + r * 128 + 4 * q - 128);
            a[s] += xv.x * w.x + xv.y * w.y + xv.z * w.z + xv.w * w.w;
        }
    }
    #pragma unroll
    for (int s = 0; s < 8; s++) GX2[(r0 + s) * 512 + j] = a[s];
}

// ---------------- K6: second LSTM recurrence + MLP head (grid=1) ----------------
__global__ __attribute__((amdgpu_waves_per_eu(2, 2))) __launch_bounds__(512)
void k_lstm2(const float* __restrict__ GX2, const unsigned short* __restrict__ Bpk2,
             const float* __restrict__ denseW, const float* __restrict__ denseb,
             const float* __restrict__ clfW, const float* __restrict__ clfb,
             float* __restrict__ out)
{
    __shared__ __align__(16) float gatebuf[4][128][8];
    __shared__ __align__(16) unsigned short ahi[8][136];
    __shared__ __align__(16) unsigned short alo[8][136];
    __shared__ float hfin[8][128];
    __shared__ float zbuf[8][32];
    lstm_core<0, 1>(GX2, Bpk2, nullptr, 0, gatebuf, ahi, alo, hfin);
    __syncthreads();
    int tid = threadIdx.x;
    if (tid < 256) {
        int b = tid >> 5, zj = tid & 31;
        float acc = denseb[zj];
        const float* dw = denseW + zj * 128;
        for (int k = 0; k < 128; k++) acc += hfin[b][k] * dw[k];
        zbuf[b][zj] = acc;
    }
    __syncthreads();
    if (tid < 16) {
        int b = tid >> 1, oj = tid & 1;
        float acc = clfb[oj];
        const float* cw = clfW + oj * 32;
        #pragma unroll
        for (int m = 0; m < 32; m++) acc += zbuf[b][m] * cw[m];
        out[b * 2 + oj] = acc;
    }
}

extern "C" void kernel_launch(void* const* d_in, const int* in_sizes, int n_in,
                              void* d_out, int out_size, void* d_ws, size_t ws_size,
                              hipStream_t stream) {
    const float* A     = (const float*)d_in[0];
    const float* Wx_W  = (const float*)d_in[1];
    const float* Wx_b  = (const float*)d_in[2];
    const float* Wxh_W = (const float*)d_in[3];
    const float* Wxh_b = (const float*)d_in[4];
    const float* Att_W = (const float*)d_in[5];
    const float* Att_b = (const float*)d_in[6];
    const float* Wih_f = (const float*)d_in[7];
    const float* Whh_f = (const float*)d_in[8];
    const float* bih_f = (const float*)d_in[9];
    const float* bhh_f = (const float*)d_in[10];
    const float* Wih_r = (const float*)d_in[11];
    const float* Whh_r = (const float*)d_in[12];
    const float* bih_r = (const float*)d_in[13];
    const float* bhh_r = (const float*)d_in[14];
    const float* Wih2  = (const float*)d_in[15];
    const float* Whh2  = (const float*)d_in[16];
    const float* bih2  = (const float*)d_in[17];
    const float* bhh2  = (const float*)d_in[18];
    const float* denseW = (const float*)d_in[19];
    const float* denseb = (const float*)d_in[20];
    const float* clfW   = (const float*)d_in[21];
    const float* clfb   = (const float*)d_in[22];

    float* ws = (float*)d_ws;
    float* WXb    = ws + OFF_WX;
    float* PXb    = ws + OFF_PX;
    float* Xb     = ws + OFF_X;
    float* GXF    = ws + OFF_GXF;
    float* GXR    = ws + OFF_GXR;
    float* HF     = ws + OFF_HF;
    float* HR     = ws + OFF_HR;
    float* GX2    = ws + OFF_GX2;
    unsigned short* BpkF = (unsigned short*)(ws + OFF_BPKF);
    unsigned short* BpkR = (unsigned short*)(ws + OFF_BPKR);
    unsigned short* Bpk2 = (unsigned short*)(ws + OFF_BPK2);
    float* wihTqf = ws + OFF_WIHTQ_F;
    float* wihTqr = ws + OFF_WIHTQ_R;
    float* wihT2q = ws + OFF_WIHT2Q;
    float* biasf  = ws + OFF_BIASF;
    float* biasr  = ws + OFF_BIASR;
    float* bias2  = ws + OFF_BIAS2;

    k_prep<<<512, 256, 0, stream>>>(Wih_f, Wih_r, Wih2, Whh_f, Whh_r, Whh2,
                                    bih_f, bhh_f, bih_r, bhh_r, bih2, bhh2,
                                    wihTqf, wihTqr, wihT2q,
                                    BpkF, BpkR, Bpk2,
                                    biasf, biasr, bias2);
    k_qk<<<B_ * S_, 64, 0, stream>>>(A, Wx_W, Wx_b, Wxh_W, Wxh_b, WXb, PXb);
    k_attn<<<B_ * (S_ / 4), 256, 0, stream>>>(A, WXb, PXb, Att_W, Att_b, Xb);
    k_gx<<<128, 512, 0, stream>>>(Xb, wihTqf, wihTqr, biasf, biasr, GXF, GXR);
    k_lstm_bi<<<2, 512, 0, stream>>>(GXF, GXR, BpkF, BpkR, HF, HR);
    k_gx2<<<128, 512, 0, stream>>>(HF, HR, wihT2q, bias2, GX2);
    k_lstm2<<<1, 512, 0, stream>>>(GX2, Bpk2, denseW, denseb, clfW, clfb,
                                   (float*)d_out);
}